// Round 1
// baseline (2001.562 us; speedup 1.0000x reference)
//
#include <hip/hip_runtime.h>
#include <math.h>

// ExpertChoice: B=1024, N=E=8, D=768, K=4, KD=3072, ND=6144, NC=1000
// Stages: router(top4,fp64)+gather -> expert fc1(gelu)/fc2 [bf16 MFMA]
//         -> sw fc1(gelu) -> sw fc2 (wave reduce) -> softmax+combine
//         -> head fc1(gelu) -> head fc2 -> out fp32 [1024,1000]

#define B_  1024
#define N_  8
#define E_  8
#define D_  768
#define KD_ 3072
#define ND_ 6144
#define NC_ 1000

typedef __attribute__((ext_vector_type(8))) short v8s;   // 8 bf16 = 4 VGPRs
typedef __attribute__((ext_vector_type(4))) float v4f;

__device__ __forceinline__ float gelu_f(float x) {
    return 0.5f * x * (1.0f + erff(x * 0.70710678118654752f));
}

__device__ __forceinline__ unsigned pk2(float a, float b) {
    union { __bf16 h[2]; unsigned u; } x;
    x.h[0] = (__bf16)a; x.h[1] = (__bf16)b;
    return x.u;
}

// ---------------- router + gather + x->bf16 ----------------
// one wave per (b,n); fp64 logits so top-4 ordering matches a high-precision ref
__global__ __launch_bounds__(256) void router_gather(
    const float* __restrict__ x, const float* __restrict__ emb,
    __bf16* __restrict__ sel, __bf16* __restrict__ xbf)
{
    int wid  = blockIdx.x * 4 + (threadIdx.x >> 6);
    int lane = threadIdx.x & 63;
    int b = wid >> 3, n = wid & 7;
    const float* xr = x + ((size_t)b * N_ + n) * D_;

    double lg[E_];
    #pragma unroll
    for (int e = 0; e < E_; ++e) {
        const float* er = emb + e * D_;
        double acc = 0.0;
        for (int d = lane; d < D_; d += 64)
            acc += (double)xr[d] * (double)er[d];
        #pragma unroll
        for (int off = 32; off > 0; off >>= 1)
            acc += __shfl_xor(acc, off, 64);
        lg[e] = acc;
    }
    unsigned used = 0;
    int idx[4];
    #pragma unroll
    for (int j = 0; j < 4; ++j) {
        int bi = -1; double bv = 0.0;
        #pragma unroll
        for (int e = 0; e < E_; ++e) {
            if (!(used & (1u << e)) && (bi < 0 || lg[e] > bv)) { bv = lg[e]; bi = e; }
        }
        used |= 1u << bi; idx[j] = bi;
    }
    // sel[n][b][j*D + d] = x[b, idx[j], d]
    __bf16* dst = sel + ((size_t)n * B_ + b) * KD_;
    #pragma unroll
    for (int j = 0; j < 4; ++j) {
        const float* src = x + ((size_t)b * N_ + idx[j]) * D_;
        for (int d = lane; d < D_; d += 64)
            dst[j * D_ + d] = (__bf16)src[d];
    }
    __bf16* xd = xbf + (size_t)b * ND_ + n * D_;
    for (int d = lane; d < D_; d += 64) xd[d] = (__bf16)xr[d];
}

// ---------------- generic GEMM: C = act(A @ W + bias) ----------------
// A: [M,K] bf16 row-major;  W: [K,N] fp32 row-major (converted to bf16 in LDS)
// 128x128 tile, BK=32, 4 waves each 64x64 via 4x4 mfma_16x16x32_bf16.
// Bs layout: k-pairs packed in dwords, word = g*528 + n*4 + j2 (pair p = g*4+j2,
// k = 2p,2p+1) -> B-frag = one ds_read_b128/lane. Write rotation breaks the
// 8-row-stride bank collision (stride 8 rows * 4 words == 32 banks).
template<bool GELU, bool OUT_BF16>
__global__ __launch_bounds__(256, 2) void gemm_bias_act(
    const __bf16* __restrict__ Ag, const float* __restrict__ Wg,
    const float* __restrict__ biasg, void* __restrict__ Cg,
    int M, int N, int K,
    long long sA, long long sW, long long sBias, long long sC)
{
    const int bz = blockIdx.z;
    const __bf16* A   = Ag    + (size_t)bz * sA;
    const float*  W   = Wg    + (size_t)bz * sW;
    const float*  bias= biasg + (size_t)bz * sBias;

    __shared__ __attribute__((aligned(16))) __bf16    As[128 * 40];  // +8 pad
    __shared__ __attribute__((aligned(16))) unsigned  Bs[4 * 528];   // [g][n][j2]

    const int tid  = threadIdx.x;
    const int lane = tid & 63;
    const int g    = lane >> 4;
    const int l16  = lane & 15;
    const int wave = tid >> 6;
    const int m0 = blockIdx.y * 128;
    const int n0 = blockIdx.x * 128;
    const int wm = (wave >> 1) * 64;
    const int wn = (wave & 1) * 64;

    const int am = tid >> 1;            // A-stage row
    const int ak = (tid & 1) * 16;      // A-stage col half
    const int bp = tid >> 4;            // B-stage k-pair 0..15
    const int bg = bp >> 2, bj = bp & 3;
    const int bn = (tid & 15) * 8;      // B-stage n base
    const int rot = tid & 15;

    v4f acc[4][4] = {};

    const int kIters = K >> 5;
    for (int kt = 0; kt < kIters; ++kt) {
        const int k0 = kt << 5;
        // global loads first (overlap with other waves' compute)
        const __bf16* ap = A + (size_t)(m0 + am) * K + (k0 + ak);
        uint4 av0 = *(const uint4*)ap;
        uint4 av1 = *(const uint4*)(ap + 8);
        const float* w0p = W + (size_t)(k0 + 2 * bp) * N + (n0 + bn);
        const float* w1p = w0p + N;
        float wa[8], wb[8];
        if (n0 + bn + 8 <= N) {
            float4 t0 = *(const float4*)(w0p);
            float4 t1 = *(const float4*)(w0p + 4);
            float4 t2 = *(const float4*)(w1p);
            float4 t3 = *(const float4*)(w1p + 4);
            wa[0]=t0.x; wa[1]=t0.y; wa[2]=t0.z; wa[3]=t0.w;
            wa[4]=t1.x; wa[5]=t1.y; wa[6]=t1.z; wa[7]=t1.w;
            wb[0]=t2.x; wb[1]=t2.y; wb[2]=t2.z; wb[3]=t2.w;
            wb[4]=t3.x; wb[5]=t3.y; wb[6]=t3.z; wb[7]=t3.w;
        } else {
            #pragma unroll
            for (int i = 0; i < 8; ++i) {
                int c = n0 + bn + i;
                wa[i] = (c < N) ? w0p[i] : 0.0f;
                wb[i] = (c < N) ? w1p[i] : 0.0f;
            }
        }
        __syncthreads();   // previous iter's frags fully consumed
        *(uint4*)&As[am * 40 + ak]     = av0;
        *(uint4*)&As[am * 40 + ak + 8] = av1;
        #pragma unroll
        for (int j = 0; j < 8; ++j) {
            int i = (j + rot) & 7;     // rotation -> 2-way banks (free)
            Bs[bg * 528 + (bn + i) * 4 + bj] = pk2(wa[i], wb[i]);
        }
        __syncthreads();
        v8s af[4], bf[4];
        #pragma unroll
        for (int mi = 0; mi < 4; ++mi)
            af[mi] = *(const v8s*)&As[(wm + mi * 16 + l16) * 40 + g * 8];
        #pragma unroll
        for (int ni = 0; ni < 4; ++ni)
            bf[ni] = *(const v8s*)&Bs[g * 528 + (wn + ni * 16 + l16) * 4];
        #pragma unroll
        for (int mi = 0; mi < 4; ++mi)
            #pragma unroll
            for (int ni = 0; ni < 4; ++ni)
                acc[mi][ni] = __builtin_amdgcn_mfma_f32_16x16x32_bf16(
                    af[mi], bf[ni], acc[mi][ni], 0, 0, 0);
    }

    // epilogue: C/D layout col=lane&15, row=(lane>>4)*4+r  (m89-verified)
    #pragma unroll
    for (int mi = 0; mi < 4; ++mi) {
        #pragma unroll
        for (int ni = 0; ni < 4; ++ni) {
            int col = n0 + wn + ni * 16 + l16;
            if (col < N) {
                float bc = bias[col];
                #pragma unroll
                for (int r = 0; r < 4; ++r) {
                    int row = m0 + wm + mi * 16 + g * 4 + r;
                    float v = acc[mi][ni][r] + bc;
                    if (GELU) v = gelu_f(v);
                    if (OUT_BF16)
                        ((__bf16*)Cg)[(size_t)bz * sC + (size_t)row * N + col] = (__bf16)v;
                    else
                        ((float*)Cg)[(size_t)bz * sC + (size_t)row * N + col] = v;
                }
            }
        }
    }
}

// ---------------- sw fc2: wlog[b,e] = Hs[b,:] . swW2[:,e] + swb2[e] ----------------
__global__ __launch_bounds__(256) void sw_fc2(
    const __bf16* __restrict__ Hs, const float* __restrict__ swW2,
    const float* __restrict__ swb2, float* __restrict__ wlog)
{
    int wid  = blockIdx.x * 4 + (threadIdx.x >> 6);
    int lane = threadIdx.x & 63;
    int b = wid >> 3, e = wid & 7;
    const __bf16* hr = Hs + (size_t)b * ND_;
    float acc = 0.f;
    for (int i = lane; i < ND_; i += 64)
        acc += (float)hr[i] * swW2[(size_t)i * E_ + e];
    #pragma unroll
    for (int off = 32; off > 0; off >>= 1)
        acc += __shfl_xor(acc, off, 64);
    if (lane == 0) wlog[b * E_ + e] = acc + swb2[e];
}

// ---------------- softmax(wlog) + combine: ws[b,k] = sum_e ER[e,b,k]*w[b,e] ----------------
__global__ __launch_bounds__(256) void combine_ws(
    const __bf16* __restrict__ ER, const float* __restrict__ wlog,
    __bf16* __restrict__ ws)
{
    int b = blockIdx.y;
    int k = blockIdx.x * 256 + threadIdx.x;
    float l[E_];
    float mx = -1e30f;
    #pragma unroll
    for (int e = 0; e < E_; ++e) { l[e] = wlog[b * E_ + e]; mx = fmaxf(mx, l[e]); }
    float s = 0.f;
    #pragma unroll
    for (int e = 0; e < E_; ++e) { l[e] = expf(l[e] - mx); s += l[e]; }
    float inv = 1.0f / s;
    float acc = 0.f;
    #pragma unroll
    for (int e = 0; e < E_; ++e)
        acc += (float)ER[((size_t)e * B_ + b) * KD_ + k] * l[e];
    ws[(size_t)b * KD_ + k] = (__bf16)(acc * inv);
}

extern "C" void kernel_launch(void* const* d_in, const int* in_sizes, int n_in,
                              void* d_out, int out_size, void* d_ws, size_t ws_size,
                              hipStream_t stream)
{
    const float* x    = (const float*)d_in[0];
    const float* emb  = (const float*)d_in[1];
    const float* W1   = (const float*)d_in[2];
    const float* b1   = (const float*)d_in[3];
    const float* W2   = (const float*)d_in[4];
    const float* b2   = (const float*)d_in[5];
    const float* swW1 = (const float*)d_in[6];
    const float* swb1 = (const float*)d_in[7];
    const float* swW2 = (const float*)d_in[8];
    const float* swb2 = (const float*)d_in[9];
    const float* chW1 = (const float*)d_in[10];
    const float* chb1 = (const float*)d_in[11];
    const float* chW2 = (const float*)d_in[12];
    const float* chb2 = (const float*)d_in[13];

    char* wsp = (char*)d_ws;
    size_t off = 0;
    auto alloc = [&](size_t bytes) -> void* {
        void* p = wsp + off;
        off = (off + bytes + 255) & ~(size_t)255;
        return p;
    };
    __bf16* sel  = (__bf16*)alloc((size_t)E_ * B_ * KD_ * 2);  // later reused as ER
    __bf16* H    = (__bf16*)alloc((size_t)E_ * B_ * KD_ * 2);
    __bf16* xbf  = (__bf16*)alloc((size_t)B_ * ND_ * 2);
    __bf16* Hs   = (__bf16*)alloc((size_t)B_ * ND_ * 2);
    float*  wlog = (float*)alloc((size_t)B_ * E_ * 4);
    __bf16* wsb  = (__bf16*)alloc((size_t)B_ * KD_ * 2);
    __bf16* T    = (__bf16*)alloc((size_t)B_ * KD_ * 2);
    __bf16* ER   = sel;   // sel dead after fc1 (kernel-boundary ordered)

    router_gather<<<dim3(B_ * N_ / 4), 256, 0, stream>>>(x, emb, sel, xbf);

    // expert fc1: H = gelu(sel @ W1 + b1)   [e batched via grid.z]
    gemm_bias_act<true, true><<<dim3(24, 8, 8), 256, 0, stream>>>(
        sel, W1, b1, H, B_, KD_, KD_,
        (long long)B_ * KD_, (long long)KD_ * KD_, (long long)KD_, (long long)B_ * KD_);
    // expert fc2: ER = H @ W2 + b2
    gemm_bias_act<false, true><<<dim3(24, 8, 8), 256, 0, stream>>>(
        H, W2, b2, ER, B_, KD_, KD_,
        (long long)B_ * KD_, (long long)KD_ * KD_, (long long)KD_, (long long)B_ * KD_);
    // sw fc1: Hs = gelu(xbf @ swW1 + swb1)
    gemm_bias_act<true, true><<<dim3(48, 8, 1), 256, 0, stream>>>(
        xbf, swW1, swb1, Hs, B_, ND_, ND_, 0, 0, 0, 0);
    sw_fc2<<<dim3(B_ * E_ / 4), 256, 0, stream>>>(Hs, swW2, swb2, wlog);
    combine_ws<<<dim3(KD_ / 256, B_), 256, 0, stream>>>(ER, wlog, wsb);
    // head fc1: T = gelu(wsb @ chW1 + chb1)
    gemm_bias_act<true, true><<<dim3(24, 8, 1), 256, 0, stream>>>(
        wsb, chW1, chb1, T, B_, KD_, KD_, 0, 0, 0, 0);
    // head fc2: out = T @ chW2 + chb2   (fp32 out, N=1000 guarded)
    gemm_bias_act<false, false><<<dim3(8, 8, 1), 256, 0, stream>>>(
        T, chW2, chb2, (float*)d_out, B_, NC_, KD_, 0, 0, 0, 0);
}